// Round 1
// baseline (94.863 us; speedup 1.0000x reference)
//
#include <hip/hip_runtime.h>
#include <math.h>

#define Bdim 32
#define Sdim 2048
#define Hdim 1024

// ws layout (in floats)
#define OFF_SCORES 0          // B*S = 65536
#define OFF_U      65536      // B*H = 32768
#define OFF_PM     98304      // 2048 per-wave maxes
#define OFF_PL     100352     // 2048 per-wave sums
#define OFF_PACC   102400     // 2048 * 1024 partial contexts
#define OFF_UPART  102400     // aliased: 32*32*1024 (dead before PACC written)
#define OFF_TC     2199552    // B*2H tanh(concat) = 65536
// total = 2265088 floats = ~8.7 MiB

__device__ __forceinline__ float dot4(float4 a, float4 b) {
    return a.x*b.x + a.y*b.y + a.z*b.z + a.w*b.w;
}

// ---- k0: partial u[b,h] = sum_g state[b,g] * Wa[g,h], split over g-chunks ----
__global__ void __launch_bounds__(256) k0_u_partial(
        const float* __restrict__ state, const float* __restrict__ Wa,
        float* __restrict__ upart) {
    __shared__ float st[32][32];            // [b][g within chunk]
    const int hc = blockIdx.x;              // 0..3  (h chunk of 256)
    const int gc = blockIdx.y;              // 0..31 (g chunk of 32)
    const int t  = threadIdx.x;
    for (int i = t; i < 1024; i += 256) {
        int b = i >> 5, g = i & 31;
        st[b][g] = state[b * Hdim + gc * 32 + g];
    }
    __syncthreads();
    float acc[32];
#pragma unroll
    for (int b = 0; b < 32; ++b) acc[b] = 0.f;
    const int h = hc * 256 + t;
    for (int g = 0; g < 32; ++g) {
        float w = Wa[(size_t)(gc * 32 + g) * Hdim + h];
#pragma unroll
        for (int b = 0; b < 32; ++b) acc[b] += st[b][g] * w;
    }
    for (int b = 0; b < 32; ++b)
        upart[((size_t)gc * 32 + b) * Hdim + h] = acc[b];
}

// ---- k1: u = sum over g-chunks of upart ----
__global__ void __launch_bounds__(256) k1_u_combine(
        const float* __restrict__ upart, float* __restrict__ u) {
    const int i = blockIdx.x * 256 + threadIdx.x;   // 0..32767 = b*H + h
    float s = 0.f;
    for (int gc = 0; gc < 32; ++gc) s += upart[(size_t)gc * 32768 + i];
    u[i] = s;
}

// ---- k2: single pass over enc: scores + online-softmax context partials ----
__global__ void __launch_bounds__(256) k2_main(
        const float* __restrict__ enc, const float* __restrict__ u,
        float* __restrict__ scores, float* __restrict__ pm,
        float* __restrict__ pl, float* __restrict__ pacc) {
    const int sc   = blockIdx.x;            // 0..15, 128 rows per block
    const int b    = blockIdx.y;            // 0..31
    const int t    = threadIdx.x;
    const int wv   = t >> 6;                // wave 0..3, 32 rows each
    const int lane = t & 63;

    // lane's 16 u values: h = i*256 + lane*4 + j  (contiguous float4 per instr)
    float uf[16];
    const float4* u4 = reinterpret_cast<const float4*>(u + (size_t)b * Hdim);
#pragma unroll
    for (int i = 0; i < 4; ++i) {
        float4 v = u4[i * 64 + lane];
        uf[4*i] = v.x; uf[4*i+1] = v.y; uf[4*i+2] = v.z; uf[4*i+3] = v.w;
    }

    float acc[16];
#pragma unroll
    for (int j = 0; j < 16; ++j) acc[j] = 0.f;
    float m = -INFINITY, l = 0.f;

    const int s0 = sc * 128 + wv * 32;
    for (int r = 0; r < 32; ++r) {
        const float4* row4 =
            reinterpret_cast<const float4*>(enc + ((size_t)b * Sdim + s0 + r) * Hdim);
        float x[16];
#pragma unroll
        for (int i = 0; i < 4; ++i) {
            float4 v = row4[i * 64 + lane];
            x[4*i] = v.x; x[4*i+1] = v.y; x[4*i+2] = v.z; x[4*i+3] = v.w;
        }
        float d = 0.f;
#pragma unroll
        for (int j = 0; j < 16; ++j) d += x[j] * uf[j];
#pragma unroll
        for (int off = 32; off >= 1; off >>= 1) d += __shfl_xor(d, off, 64);
        if (lane == 0) scores[(size_t)b * Sdim + s0 + r] = d;

        if (d > m) {                         // wave-uniform branch
            float al = __expf(m - d);        // exp(-inf)=0 on first hit
#pragma unroll
            for (int j = 0; j < 16; ++j) acc[j] *= al;
            l *= al;
            m = d;
        }
        float p = __expf(d - m);
#pragma unroll
        for (int j = 0; j < 16; ++j) acc[j] += p * x[j];
        l += p;
    }

    const int widx = (b * 16 + sc) * 4 + wv;     // = b*64 + sc*4 + wv
    if (lane == 0) { pm[widx] = m; pl[widx] = l; }
    float4* pa = reinterpret_cast<float4*>(pacc + (size_t)widx * Hdim);
#pragma unroll
    for (int i = 0; i < 4; ++i) {
        float4 v = make_float4(acc[4*i], acc[4*i+1], acc[4*i+2], acc[4*i+3]);
        pa[i * 64 + lane] = v;
    }
}

// ---- k3: per-b combine partials -> context, tanh(concat), softmax output ----
__global__ void __launch_bounds__(256) k3_combine(
        const float* __restrict__ pm, const float* __restrict__ pl,
        const float* __restrict__ pacc, const float* __restrict__ scores,
        const float* __restrict__ state,
        float* __restrict__ tc, float* __restrict__ sm_out) {
    const int b = blockIdx.x;
    const int t = threadIdx.x;
    __shared__ float e[64];
    __shared__ float MS, LS;
    if (t < 64) {
        float mi = pm[b * 64 + t];
        float M = mi;
#pragma unroll
        for (int off = 32; off >= 1; off >>= 1) M = fmaxf(M, __shfl_xor(M, off, 64));
        float ee = __expf(mi - M);
        float Li = ee * pl[b * 64 + t];
#pragma unroll
        for (int off = 32; off >= 1; off >>= 1) Li += __shfl_xor(Li, off, 64);
        e[t] = ee;
        if (t == 0) { MS = M; LS = Li; }
    }
    __syncthreads();
    const float M = MS, invL = 1.f / LS;

    // context for h = t*4 .. t*4+3
    float4 c = make_float4(0.f, 0.f, 0.f, 0.f);
    for (int i = 0; i < 64; ++i) {
        const float4 a = *reinterpret_cast<const float4*>(
            pacc + ((size_t)(b * 64 + i)) * Hdim + t * 4);
        float ee = e[i];
        c.x += ee * a.x; c.y += ee * a.y; c.z += ee * a.z; c.w += ee * a.w;
    }
    float4 tcv = make_float4(tanhf(c.x * invL), tanhf(c.y * invL),
                             tanhf(c.z * invL), tanhf(c.w * invL));
    *reinterpret_cast<float4*>(tc + (size_t)b * 2048 + t * 4) = tcv;

    const float4 sv = *reinterpret_cast<const float4*>(state + (size_t)b * Hdim + t * 4);
    float4 tsv = make_float4(tanhf(sv.x), tanhf(sv.y), tanhf(sv.z), tanhf(sv.w));
    *reinterpret_cast<float4*>(tc + (size_t)b * 2048 + 1024 + t * 4) = tsv;

    // softmax_attn output
#pragma unroll
    for (int i = 0; i < 8; ++i) {
        int s = i * 256 + t;
        sm_out[(size_t)b * Sdim + s] = __expf(scores[(size_t)b * Sdim + s] - M) * invL;
    }
}

// ---- k4: out[b,o] = relu( sum_k tc[b,k] * Wc[o,k] + Wcb[o] ), 2 o per block ----
__global__ void __launch_bounds__(256) k4_out(
        const float* __restrict__ tc, const float* __restrict__ Wc,
        const float* __restrict__ Wcb, float* __restrict__ out) {
    __shared__ float red[64][4];      // [b*2+oo][wave]
    const int o0 = blockIdx.x * 2;
    const int t = threadIdx.x;
    const int wv = t >> 6, lane = t & 63;
    const int k0 = t * 8;

    const float4* w0 = reinterpret_cast<const float4*>(Wc + (size_t)o0 * 2048 + k0);
    const float4* w1 = reinterpret_cast<const float4*>(Wc + (size_t)(o0 + 1) * 2048 + k0);
    const float4 w00 = w0[0], w01 = w0[1], w10 = w1[0], w11 = w1[1];

    for (int b = 0; b < 32; ++b) {
        const float4* a4 = reinterpret_cast<const float4*>(tc + (size_t)b * 2048 + k0);
        float4 a0 = a4[0], a1 = a4[1];
        float p0 = dot4(w00, a0) + dot4(w01, a1);
        float p1 = dot4(w10, a0) + dot4(w11, a1);
#pragma unroll
        for (int off = 32; off >= 1; off >>= 1) {
            p0 += __shfl_xor(p0, off, 64);
            p1 += __shfl_xor(p1, off, 64);
        }
        if (lane == 0) { red[2*b][wv] = p0; red[2*b+1][wv] = p1; }
    }
    __syncthreads();
    if (t < 64) {
        float v = red[t][0] + red[t][1] + red[t][2] + red[t][3];
        int b = t >> 1, o = o0 + (t & 1);
        out[(size_t)b * Hdim + o] = fmaxf(v + Wcb[o], 0.f);
    }
}

extern "C" void kernel_launch(void* const* d_in, const int* in_sizes, int n_in,
                              void* d_out, int out_size, void* d_ws, size_t ws_size,
                              hipStream_t stream) {
    const float* enc   = (const float*)d_in[0];   // [B,S,H]
    const float* ts    = (const float*)d_in[1];   // [1,B,H]
    const float* Wa    = (const float*)d_in[2];   // [H,H]
    const float* Wc    = (const float*)d_in[3];   // [H,2H]
    const float* Wcb   = (const float*)d_in[4];   // [H]
    float* out = (float*)d_out;                   // [B*H output | B*S softmax]
    float* ws  = (float*)d_ws;

    float* scores = ws + OFF_SCORES;
    float* u      = ws + OFF_U;
    float* pm     = ws + OFF_PM;
    float* pl     = ws + OFF_PL;
    float* pacc   = ws + OFF_PACC;
    float* upart  = ws + OFF_UPART;
    float* tc     = ws + OFF_TC;

    k0_u_partial<<<dim3(4, 32), 256, 0, stream>>>(ts, Wa, upart);
    k1_u_combine<<<dim3(128), 256, 0, stream>>>(upart, u);
    k2_main<<<dim3(16, 32), 256, 0, stream>>>(enc, u, scores, pm, pl, pacc);
    k3_combine<<<dim3(32), 256, 0, stream>>>(pm, pl, pacc, scores, ts,
                                             tc, out + Bdim * Hdim);
    k4_out<<<dim3(512), 256, 0, stream>>>(tc, Wc, Wcb, out);
}